// Round 8
// baseline (299.386 us; speedup 1.0000x reference)
//
#include <hip/hip_runtime.h>
#include <cstdint>
#include <cstddef>

constexpr int SEQ  = 2048;
constexpr int CH   = 1024;
constexpr int NH   = 16;
constexpr int HS   = 64;
constexpr int NB   = 2;
constexpr int HDIM = NH * HS; // 1024

typedef __bf16 bf16x8 __attribute__((ext_vector_type(8)));
typedef float  f32x4  __attribute__((ext_vector_type(4)));

__device__ __forceinline__ unsigned short f2bf(float f) {
  union { float f; unsigned u; } v; v.f = f;
  unsigned u = v.u;
  u += 0x7fffu + ((u >> 16) & 1u);   // RNE
  return (unsigned short)(u >> 16);
}
__device__ __forceinline__ unsigned short f2bf_fast(float f) {
  union { float f; unsigned u; } v; v.f = f;
  return (unsigned short)((v.u + 0x8000u) >> 16);
}
__device__ __forceinline__ float bf2f(unsigned short h) {
  union { unsigned u; float f; } v; v.u = ((unsigned)h) << 16;
  return v.f;
}
__device__ __forceinline__ float load_elem(const void* p, int flag, size_t idx) {
  if (flag) return ((const float*)p)[idx];
  return bf2f(((const unsigned short*)p)[idx]);
}
__device__ __forceinline__ void gl_lds16(const unsigned short* g, unsigned short* l) {
  __builtin_amdgcn_global_load_lds(
      (const __attribute__((address_space(1))) unsigned int*)g,
      (__attribute__((address_space(3))) unsigned int*)l, 16, 0, 0);
}

// ---- inline dtype detector: sample n even ushorts of p, block-parallel.
// fp32 storage -> even shorts are mantissa garbage (~24% sane) ; bf16 -> ~100%.
__device__ int detect_flag_block(const void* p, int n, int tid, int nthr) {
  __shared__ int det_good;
  if (tid == 0) det_good = 0;
  __syncthreads();
  const unsigned short* u = (const unsigned short*)p;
  int good = 0;
  for (int j = tid; j < n; j += nthr) {
    unsigned short v = u[2 * j];
    int e = (v >> 7) & 0xFF;
    if (v != 0 && e >= 90 && e <= 150) good++;
  }
  atomicAdd(&det_good, good);
  __syncthreads();
  return (det_good * 10 >= n * 7) ? 0 : 1;   // 0 = bf16, 1 = fp32
}

// ---- ingest x -> bf16 (vectorized) ----
__global__ void ingest_x(const void* __restrict__ x, unsigned short* __restrict__ xb) {
  int f = detect_flag_block(x, 512, threadIdx.x, blockDim.x);
  size_t n4 = (size_t)NB * SEQ * CH / 4;
  for (size_t i = (size_t)blockIdx.x * blockDim.x + threadIdx.x; i < n4;
       i += (size_t)gridDim.x * blockDim.x) {
    ushort4 o;
    if (f) {
      float4 v = ((const float4*)x)[i];
      o.x = f2bf(v.x); o.y = f2bf(v.y); o.z = f2bf(v.z); o.w = f2bf(v.w);
    } else {
      o = ((const ushort4*)x)[i];
    }
    ((ushort4*)xb)[i] = o;
  }
}

// ---- fused transpose of Wq/Wk/Wv: [H,C,D] -> [H,D,C] bf16 (z = which*16 + h) ----
__global__ void transpose3_k(const void* __restrict__ wq, const void* __restrict__ wk,
                             const void* __restrict__ wv,
                             unsigned short* __restrict__ dst) {  // [3][H][D][C]
  __shared__ unsigned short tile[32][33];
  int z = blockIdx.z, which = z >> 4, hh = z & 15;
  const void* src = (which == 0) ? wq : (which == 1) ? wk : wv;
  int tid = threadIdx.y * 32 + threadIdx.x;
  int f = detect_flag_block(src, 512, tid, 256);
  size_t boff = (size_t)hh * CH * HS;
  int c0 = blockIdx.x * 32, r0 = blockIdx.y * 32;
  for (int i = threadIdx.y; i < 32; i += 8)
    tile[i][threadIdx.x] = f2bf(load_elem(src, f, boff + (size_t)(r0 + i) * HS + c0 + threadIdx.x));
  __syncthreads();
  unsigned short* d = dst + ((size_t)which * NH + hh) * HS * CH;
  for (int i = threadIdx.y; i < 32; i += 8)
    d[(size_t)(c0 + i) * CH + r0 + threadIdx.x] = tile[threadIdx.x][i];
}

// ---- transpose Wo: [HD,C] -> [C,HD] bf16 ----
__global__ void transpose_k(const void* __restrict__ src,
                            unsigned short* __restrict__ dst,
                            int rows, int cols) {
  __shared__ unsigned short tile[32][33];
  int tid = threadIdx.y * 32 + threadIdx.x;
  int f = detect_flag_block(src, 512, tid, 256);
  int c0 = blockIdx.x * 32, r0 = blockIdx.y * 32;
  for (int i = threadIdx.y; i < 32; i += 8)
    tile[i][threadIdx.x] = f2bf(load_elem(src, f, (size_t)(r0 + i) * cols + c0 + threadIdx.x));
  __syncthreads();
  for (int i = threadIdx.y; i < 32; i += 8)
    dst[(size_t)(c0 + i) * rows + r0 + threadIdx.x] = tile[threadIdx.x][i];
}

// ---- fused QKV GEMM, m97-style staging + XOR swizzle ----
// q pre-scaled by 0.125*log2(e) so attention uses exp2 directly.
__global__ __launch_bounds__(256) void qkv_gemm(
    const unsigned short* __restrict__ xb,
    const unsigned short* __restrict__ wall,   // [3072][1024]
    unsigned short* __restrict__ qo,
    unsigned short* __restrict__ ko,
    unsigned short* __restrict__ vt) {
  __shared__ __attribute__((aligned(16))) unsigned short Al[128 * 64];
  __shared__ __attribute__((aligned(16))) unsigned short Bl[128 * 64];
  int mt = blockIdx.x, nt = blockIdx.y;
  const unsigned short* A  = xb   + (size_t)mt * 128 * CH;
  const unsigned short* Bm = wall + (size_t)nt * 128 * CH;
  int tid = threadIdx.x, wave = tid >> 6, lane = tid & 63;
  int quad = lane >> 4, l15 = lane & 15;
  int r8 = lane >> 3, c8 = lane & 7;
  int gcol = ((c8 ^ r8) << 3);
  int x7 = l15 & 7;
  int wm = (wave >> 1) * 64, wn = (wave & 1) * 64;
  f32x4 acc[4][4];
  #pragma unroll
  for (int i = 0; i < 4; i++)
    #pragma unroll
    for (int j = 0; j < 4; j++) acc[i][j] = (f32x4){0.f, 0.f, 0.f, 0.f};

  for (int k0 = 0; k0 < CH; k0 += 64) {
    #pragma unroll
    for (int c = 0; c < 4; c++) {
      int row = wave * 32 + c * 8 + r8;
      gl_lds16(&A [(size_t)row * CH + k0 + gcol], &Al[(wave * 32 + c * 8) * 64]);
      gl_lds16(&Bm[(size_t)row * CH + k0 + gcol], &Bl[(wave * 32 + c * 8) * 64]);
    }
    __syncthreads();
    #pragma unroll
    for (int h = 0; h < 2; h++) {
      int cq = ((quad + 4 * h) ^ x7) << 3;
      bf16x8 af[4], bfr[4];
      #pragma unroll
      for (int fm = 0; fm < 4; fm++)
        af[fm] = *reinterpret_cast<const bf16x8*>(&Al[(wm + fm * 16 + l15) * 64 + cq]);
      #pragma unroll
      for (int fn = 0; fn < 4; fn++)
        bfr[fn] = *reinterpret_cast<const bf16x8*>(&Bl[(wn + fn * 16 + l15) * 64 + cq]);
      #pragma unroll
      for (int fm = 0; fm < 4; fm++)
        #pragma unroll
        for (int fn = 0; fn < 4; fn++)
          acc[fm][fn] = __builtin_amdgcn_mfma_f32_16x16x32_bf16(af[fm], bfr[fn], acc[fm][fn], 0, 0, 0);
    }
    __syncthreads();
  }

  int seg = (nt * 128) >> 10;
  int nb  = (nt * 128) & 1023;
  if (seg < 2) {
    unsigned short* dst = (seg == 0) ? qo : ko;
    float s = (seg == 0) ? 0.18033688011112042f : 1.0f;  // 0.125*log2(e)
    #pragma unroll
    for (int fn = 0; fn < 4; fn++) {
      int c = nb + wn + fn * 16 + l15, h = c >> 6, d = c & 63;
      #pragma unroll
      for (int fm = 0; fm < 4; fm++) {
        int m = mt * 128 + wm + fm * 16 + quad * 4;
        int b = m >> 11, s0 = m & 2047;
        #pragma unroll
        for (int r = 0; r < 4; r++)
          dst[(((size_t)b * NH + h) * SEQ + s0 + r) * HS + d] = f2bf(acc[fm][fn][r] * s);
      }
    }
  } else { // v transposed: vt[b][h][d][s]
    #pragma unroll
    for (int fn = 0; fn < 4; fn++) {
      int c = nb + wn + fn * 16 + l15, h = c >> 6, d = c & 63;
      #pragma unroll
      for (int fm = 0; fm < 4; fm++) {
        int m = mt * 128 + wm + fm * 16 + quad * 4;
        int b = m >> 11, s0 = m & 2047;
        ushort4 pk;
        pk.x = f2bf(acc[fm][fn][0]); pk.y = f2bf(acc[fm][fn][1]);
        pk.z = f2bf(acc[fm][fn][2]); pk.w = f2bf(acc[fm][fn][3]);
        *(ushort4*)&vt[(((size_t)b * NH + h) * HS + d) * SEQ + s0] = pk;
      }
    }
  }
}

// ---- flash attention: 64 q-rows/block, S^T scheme, K direct-from-global,
//      V via swizzled global_load_lds dbuf, 1 barrier/tile, 25 KB LDS ----
__global__ __launch_bounds__(256) void attn_k(
    const unsigned short* __restrict__ q,
    const unsigned short* __restrict__ k,
    const unsigned short* __restrict__ vt,
    unsigned short* __restrict__ y) {
  __shared__ __attribute__((aligned(16))) unsigned short Vl[2][64 * 64];
  __shared__ __attribute__((aligned(16))) unsigned short Pt[4][16 * 72];

  int st = (int)gridDim.x - 1 - (int)blockIdx.x;   // heavy-first
  int bh = blockIdx.y, b = bh >> 4, h = bh & 15;
  const unsigned short* Q = q  + ((size_t)bh * SEQ + st * 64) * HS;
  const unsigned short* K = k  + (size_t)bh * SEQ * HS;
  const unsigned short* V = vt + (size_t)bh * HS * SEQ;   // [d][s]
  int tid = threadIdx.x, wave = tid >> 6, lane = tid & 63;
  int quad = lane >> 4, l15 = lane & 15;
  int r8 = lane >> 3, c8 = lane & 7;
  int gsw = ((c8 ^ r8) << 3);     // staging swizzle (elems)
  int x7 = l15 & 7;

  bf16x8 qf[2];
  #pragma unroll
  for (int hh = 0; hh < 2; hh++)
    qf[hh] = *reinterpret_cast<const bf16x8*>(
        &Q[(size_t)(wave * 16 + l15) * HS + hh * 32 + quad * 8]);

  float lsum = 0.f;
  f32x4 accO[4];
  #pragma unroll
  for (int i = 0; i < 4; i++) accO[i] = (f32x4){0.f, 0.f, 0.f, 0.f};

  unsigned short* ptRow = &Pt[wave][l15 * 72];
  bf16x8 kf[4][2];

  // K A-frag direct load: A[t][d], t = kv*64+tb*16+l15, k(d) = hh*32+quad*8+j
  auto loadK = [&](int kv) {
    #pragma unroll
    for (int tb = 0; tb < 4; tb++)
      #pragma unroll
      for (int hh = 0; hh < 2; hh++)
        kf[tb][hh] = *reinterpret_cast<const bf16x8*>(
            &K[(size_t)(kv * 64 + tb * 16 + l15) * HS + hh * 32 + quad * 8]);
  };
  // V staging: wave stages its 16 d-rows, swizzled chunks, via global_load_lds
  auto stageV = [&](int kv, int buf) {
    #pragma unroll
    for (int p = 0; p < 2; p++) {
      int d = wave * 16 + p * 8 + r8;
      gl_lds16(&V[(size_t)d * SEQ + kv * 64 + gsw], &Vl[buf][(wave * 16 + p * 8) * 64]);
    }
  };

  loadK(0);
  stageV(0, 0);

  for (int kv = 0; kv <= st; kv++) {
    int cb = kv & 1;
    __syncthreads();                        // V(kv) staged (vmcnt drained here)
    if (kv < st) stageV(kv + 1, cb ^ 1);    // async into other buffer

    bool diag = (kv == st);
    // S^T = K·Q^T  (skip wave-uniform fully-masked tb on the diagonal tile)
    f32x4 s[4];
    #pragma unroll
    for (int tb = 0; tb < 4; tb++) {
      s[tb] = (f32x4){0.f, 0.f, 0.f, 0.f};
      if (!diag || tb <= wave) {
        #pragma unroll
        for (int hh = 0; hh < 2; hh++)
          s[tb] = __builtin_amdgcn_mfma_f32_16x16x32_bf16(kf[tb][hh], qf[hh], s[tb], 0, 0, 0);
      }
    }
    if (kv < st) loadK(kv + 1);             // prefetch next K frags (regs free now)

    // softmax (per-lane partial sums) + pack P^T rows
    #pragma unroll
    for (int tb = 0; tb < 4; tb++) {
      ushort4 pk;
      if (!diag || tb <= wave) {
        float pv[4];
        #pragma unroll
        for (int r = 0; r < 4; r++) {
          float p = exp2f(s[tb][r]);
          if (diag && (tb * 16 + quad * 4 + r > wave * 16 + l15)) p = 0.f;
          lsum += p;
          pv[r] = p;
        }
        pk.x = f2bf_fast(pv[0]); pk.y = f2bf_fast(pv[1]);
        pk.z = f2bf_fast(pv[2]); pk.w = f2bf_fast(pv[3]);
      } else {
        pk.x = 0; pk.y = 0; pk.z = 0; pk.w = 0;
      }
      *(ushort4*)&ptRow[tb * 16 + quad * 4] = pk;
    }

    // O^T += V·P^T   (Pt wave-private; lgkmcnt covers the RAW)
    bf16x8 bq[2];
    #pragma unroll
    for (int tp = 0; tp < 2; tp++)
      bq[tp] = *reinterpret_cast<const bf16x8*>(&ptRow[tp * 32 + quad * 8]);
    #pragma unroll
    for (int db = 0; db < 4; db++)
      #pragma unroll
      for (int tp = 0; tp < 2; tp++) {
        bf16x8 vf = *reinterpret_cast<const bf16x8*>(
            &Vl[cb][(db * 16 + l15) * 64 + (((tp * 4 + quad) ^ x7) << 3)]);
        accO[db] = __builtin_amdgcn_mfma_f32_16x16x32_bf16(vf, bq[tp], accO[db], 0, 0, 0);
      }
  }

  // epilogue: reduce per-lane l over quads, normalize, write Y
  float rs = lsum;
  rs += __shfl_xor(rs, 16); rs += __shfl_xor(rs, 32);
  float inv = 1.0f / fmaxf(rs, 1e-30f);
  int srow = st * 64 + wave * 16 + l15;
  #pragma unroll
  for (int db = 0; db < 4; db++) {
    ushort4 pk;
    pk.x = f2bf(accO[db][0] * inv); pk.y = f2bf(accO[db][1] * inv);
    pk.z = f2bf(accO[db][2] * inv); pk.w = f2bf(accO[db][3] * inv);
    *(ushort4*)&y[((size_t)b * SEQ + srow) * HDIM + h * 64 + db * 16 + quad * 4] = pk;
  }
}

// ---- output projection, m97-style + swizzle -> fp32 out ----
__global__ __launch_bounds__(256) void out_gemm(
    const unsigned short* __restrict__ y,
    const unsigned short* __restrict__ wot,
    const void* __restrict__ bo,
    float* __restrict__ out) {
  __shared__ __attribute__((aligned(16))) unsigned short Al[128 * 64];
  __shared__ __attribute__((aligned(16))) unsigned short Bl[128 * 64];
  int tid = threadIdx.x;
  int fbo = detect_flag_block(bo, 512, tid, 256);
  int mt = blockIdx.x, nt = blockIdx.y;
  const unsigned short* A  = y   + (size_t)mt * 128 * HDIM;
  const unsigned short* Bm = wot + (size_t)nt * 128 * HDIM;
  int wave = tid >> 6, lane = tid & 63;
  int quad = lane >> 4, l15 = lane & 15;
  int r8 = lane >> 3, c8 = lane & 7;
  int gcol = ((c8 ^ r8) << 3);
  int x7 = l15 & 7;
  int wm = (wave >> 1) * 64, wn = (wave & 1) * 64;
  f32x4 acc[4][4];
  #pragma unroll
  for (int i = 0; i < 4; i++)
    #pragma unroll
    for (int j = 0; j < 4; j++) acc[i][j] = (f32x4){0.f, 0.f, 0.f, 0.f};

  for (int k0 = 0; k0 < HDIM; k0 += 64) {
    #pragma unroll
    for (int c = 0; c < 4; c++) {
      int row = wave * 32 + c * 8 + r8;
      gl_lds16(&A [(size_t)row * HDIM + k0 + gcol], &Al[(wave * 32 + c * 8) * 64]);
      gl_lds16(&Bm[(size_t)row * HDIM + k0 + gcol], &Bl[(wave * 32 + c * 8) * 64]);
    }
    __syncthreads();
    #pragma unroll
    for (int h = 0; h < 2; h++) {
      int cq = ((quad + 4 * h) ^ x7) << 3;
      bf16x8 af[4], bfr[4];
      #pragma unroll
      for (int fm = 0; fm < 4; fm++)
        af[fm] = *reinterpret_cast<const bf16x8*>(&Al[(wm + fm * 16 + l15) * 64 + cq]);
      #pragma unroll
      for (int fn = 0; fn < 4; fn++)
        bfr[fn] = *reinterpret_cast<const bf16x8*>(&Bl[(wn + fn * 16 + l15) * 64 + cq]);
      #pragma unroll
      for (int fm = 0; fm < 4; fm++)
        #pragma unroll
        for (int fn = 0; fn < 4; fn++)
          acc[fm][fn] = __builtin_amdgcn_mfma_f32_16x16x32_bf16(af[fm], bfr[fn], acc[fm][fn], 0, 0, 0);
    }
    __syncthreads();
  }

  #pragma unroll
  for (int fn = 0; fn < 4; fn++) {
    int n = nt * 128 + wn + fn * 16 + l15;
    float bias = load_elem(bo, fbo, n);
    #pragma unroll
    for (int fm = 0; fm < 4; fm++) {
      int m = mt * 128 + wm + fm * 16 + quad * 4;
      #pragma unroll
      for (int r = 0; r < 4; r++)
        out[(size_t)(m + r) * CH + n] = acc[fm][fn][r] + bias;
    }
  }
}

extern "C" void kernel_launch(void* const* d_in, const int* in_sizes, int n_in,
                              void* d_out, int out_size, void* d_ws, size_t ws_size,
                              hipStream_t stream) {
  const void* x  = d_in[0];
  const void* Wq = d_in[1];
  const void* Wk = d_in[2];
  const void* Wv = d_in[3];
  const void* Wo = d_in[4];
  const void* bo = d_in[5];
  float* out = (float*)d_out;

  char* ws = (char*)d_ws;
  const size_t MB = 1024 * 1024;
  unsigned short* qb   = (unsigned short*)(ws + 0);        // [B,H,S,D]  8MB (pre-scaled)
  unsigned short* kb   = (unsigned short*)(ws + 8  * MB);  // [B,H,S,D]  8MB
  unsigned short* vtb  = (unsigned short*)(ws + 16 * MB);  // [B,H,D,S]  8MB
  unsigned short* yb   = (unsigned short*)(ws + 24 * MB);  // [B,S,HD]   8MB
  unsigned short* wall = (unsigned short*)(ws + 32 * MB);  // [3][H,D,C] 6MB contiguous
  unsigned short* wot  = (unsigned short*)(ws + 38 * MB);  // [C,HD]     2MB
  unsigned short* xb   = (unsigned short*)(ws + 40 * MB);  // [B,S,C]    8MB bf16

  ingest_x<<<2048, 256, 0, stream>>>(x, xb);
  transpose3_k<<<dim3(HS / 32, CH / 32, 48), dim3(32, 8), 0, stream>>>(Wq, Wk, Wv, wall);
  transpose_k<<<dim3(CH / 32, HDIM / 32), dim3(32, 8), 0, stream>>>(Wo, wot, HDIM, CH);

  qkv_gemm<<<dim3(NB * SEQ / 128, 3 * HDIM / 128), 256, 0, stream>>>(xb, wall, qb, kb, vtb);
  attn_k  <<<dim3(SEQ / 64, NB * NH), 256, 0, stream>>>(qb, kb, vtb, yb);
  out_gemm<<<dim3(NB * SEQ / 128, CH / 128), 256, 0, stream>>>(yb, wot, bo, out);
}

// Round 9
// 286.385 us; speedup vs baseline: 1.0454x; 1.0454x over previous
//
#include <hip/hip_runtime.h>
#include <cstdint>
#include <cstddef>

constexpr int SEQ  = 2048;
constexpr int CH   = 1024;
constexpr int NH   = 16;
constexpr int HS   = 64;
constexpr int NB   = 2;
constexpr int HDIM = NH * HS; // 1024

typedef __bf16 bf16x8 __attribute__((ext_vector_type(8)));
typedef float  f32x4  __attribute__((ext_vector_type(4)));

__device__ __forceinline__ unsigned short f2bf(float f) {
  union { float f; unsigned u; } v; v.f = f;
  unsigned u = v.u;
  u += 0x7fffu + ((u >> 16) & 1u);   // RNE
  return (unsigned short)(u >> 16);
}
__device__ __forceinline__ unsigned short f2bf_fast(float f) {
  union { float f; unsigned u; } v; v.f = f;
  return (unsigned short)((v.u + 0x8000u) >> 16);
}
__device__ __forceinline__ float bf2f(unsigned short h) {
  union { unsigned u; float f; } v; v.u = ((unsigned)h) << 16;
  return v.f;
}
__device__ __forceinline__ float load_elem(const void* p, int flag, size_t idx) {
  if (flag) return ((const float*)p)[idx];
  return bf2f(((const unsigned short*)p)[idx]);
}
__device__ __forceinline__ void gl_lds16(const unsigned short* g, unsigned short* l) {
  __builtin_amdgcn_global_load_lds(
      (const __attribute__((address_space(1))) unsigned int*)g,
      (__attribute__((address_space(3))) unsigned int*)l, 16, 0, 0);
}

// ---- inline dtype detector (observed: inputs fp32; kept as insurance) ----
__device__ int detect_flag_block(const void* p, int n, int tid, int nthr) {
  __shared__ int det_good;
  if (tid == 0) det_good = 0;
  __syncthreads();
  const unsigned short* u = (const unsigned short*)p;
  int good = 0;
  for (int j = tid; j < n; j += nthr) {
    unsigned short v = u[2 * j];
    int e = (v >> 7) & 0xFF;
    if (v != 0 && e >= 90 && e <= 150) good++;
  }
  atomicAdd(&det_good, good);
  __syncthreads();
  return (det_good * 10 >= n * 7) ? 0 : 1;   // 0 = bf16, 1 = fp32
}

// ---- ingest x -> bf16 (vectorized) ----
__global__ void ingest_x(const void* __restrict__ x, unsigned short* __restrict__ xb) {
  int f = detect_flag_block(x, 512, threadIdx.x, blockDim.x);
  size_t n4 = (size_t)NB * SEQ * CH / 4;
  for (size_t i = (size_t)blockIdx.x * blockDim.x + threadIdx.x; i < n4;
       i += (size_t)gridDim.x * blockDim.x) {
    ushort4 o;
    if (f) {
      float4 v = ((const float4*)x)[i];
      o.x = f2bf(v.x); o.y = f2bf(v.y); o.z = f2bf(v.z); o.w = f2bf(v.w);
    } else {
      o = ((const ushort4*)x)[i];
    }
    ((ushort4*)xb)[i] = o;
  }
}

// ---- fused transpose of Wq/Wk/Wv: [H,C,D] -> [H,D,C] bf16 ----
__global__ void transpose3_k(const void* __restrict__ wq, const void* __restrict__ wk,
                             const void* __restrict__ wv,
                             unsigned short* __restrict__ dst) {  // [3][H][D][C]
  __shared__ unsigned short tile[32][33];
  int z = blockIdx.z, which = z >> 4, hh = z & 15;
  const void* src = (which == 0) ? wq : (which == 1) ? wk : wv;
  int tid = threadIdx.y * 32 + threadIdx.x;
  int f = detect_flag_block(src, 512, tid, 256);
  size_t boff = (size_t)hh * CH * HS;
  int c0 = blockIdx.x * 32, r0 = blockIdx.y * 32;
  for (int i = threadIdx.y; i < 32; i += 8)
    tile[i][threadIdx.x] = f2bf(load_elem(src, f, boff + (size_t)(r0 + i) * HS + c0 + threadIdx.x));
  __syncthreads();
  unsigned short* d = dst + ((size_t)which * NH + hh) * HS * CH;
  for (int i = threadIdx.y; i < 32; i += 8)
    d[(size_t)(c0 + i) * CH + r0 + threadIdx.x] = tile[threadIdx.x][i];
}

// ---- transpose Wo: [HD,C] -> [C,HD] bf16 ----
__global__ void transpose_k(const void* __restrict__ src,
                            unsigned short* __restrict__ dst,
                            int rows, int cols) {
  __shared__ unsigned short tile[32][33];
  int tid = threadIdx.y * 32 + threadIdx.x;
  int f = detect_flag_block(src, 512, tid, 256);
  int c0 = blockIdx.x * 32, r0 = blockIdx.y * 32;
  for (int i = threadIdx.y; i < 32; i += 8)
    tile[i][threadIdx.x] = f2bf(load_elem(src, f, (size_t)(r0 + i) * cols + c0 + threadIdx.x));
  __syncthreads();
  for (int i = threadIdx.y; i < 32; i += 8)
    dst[(size_t)(c0 + i) * rows + r0 + threadIdx.x] = tile[threadIdx.x][i];
}

// ---- fused QKV GEMM, m97-style staging + XOR swizzle ----
__global__ __launch_bounds__(256) void qkv_gemm(
    const unsigned short* __restrict__ xb,
    const unsigned short* __restrict__ wall,   // [3072][1024]
    unsigned short* __restrict__ qo,
    unsigned short* __restrict__ ko,
    unsigned short* __restrict__ vt) {
  __shared__ __attribute__((aligned(16))) unsigned short Al[128 * 64];
  __shared__ __attribute__((aligned(16))) unsigned short Bl[128 * 64];
  int mt = blockIdx.x, nt = blockIdx.y;
  const unsigned short* A  = xb   + (size_t)mt * 128 * CH;
  const unsigned short* Bm = wall + (size_t)nt * 128 * CH;
  int tid = threadIdx.x, wave = tid >> 6, lane = tid & 63;
  int quad = lane >> 4, l15 = lane & 15;
  int r8 = lane >> 3, c8 = lane & 7;
  int gcol = ((c8 ^ r8) << 3);
  int x7 = l15 & 7;
  int wm = (wave >> 1) * 64, wn = (wave & 1) * 64;
  f32x4 acc[4][4];
  #pragma unroll
  for (int i = 0; i < 4; i++)
    #pragma unroll
    for (int j = 0; j < 4; j++) acc[i][j] = (f32x4){0.f, 0.f, 0.f, 0.f};

  for (int k0 = 0; k0 < CH; k0 += 64) {
    #pragma unroll
    for (int c = 0; c < 4; c++) {
      int row = wave * 32 + c * 8 + r8;
      gl_lds16(&A [(size_t)row * CH + k0 + gcol], &Al[(wave * 32 + c * 8) * 64]);
      gl_lds16(&Bm[(size_t)row * CH + k0 + gcol], &Bl[(wave * 32 + c * 8) * 64]);
    }
    __syncthreads();
    #pragma unroll
    for (int h = 0; h < 2; h++) {
      int cq = ((quad + 4 * h) ^ x7) << 3;
      bf16x8 af[4], bfr[4];
      #pragma unroll
      for (int fm = 0; fm < 4; fm++)
        af[fm] = *reinterpret_cast<const bf16x8*>(&Al[(wm + fm * 16 + l15) * 64 + cq]);
      #pragma unroll
      for (int fn = 0; fn < 4; fn++)
        bfr[fn] = *reinterpret_cast<const bf16x8*>(&Bl[(wn + fn * 16 + l15) * 64 + cq]);
      #pragma unroll
      for (int fm = 0; fm < 4; fm++)
        #pragma unroll
        for (int fn = 0; fn < 4; fn++)
          acc[fm][fn] = __builtin_amdgcn_mfma_f32_16x16x32_bf16(af[fm], bfr[fn], acc[fm][fn], 0, 0, 0);
    }
    __syncthreads();
  }

  int seg = (nt * 128) >> 10;
  int nb  = (nt * 128) & 1023;
  if (seg < 2) {
    unsigned short* dst = (seg == 0) ? qo : ko;
    float s = (seg == 0) ? 0.18033688011112042f : 1.0f;  // 0.125*log2(e) folded into q
    #pragma unroll
    for (int fn = 0; fn < 4; fn++) {
      int c = nb + wn + fn * 16 + l15, h = c >> 6, d = c & 63;
      #pragma unroll
      for (int fm = 0; fm < 4; fm++) {
        int m = mt * 128 + wm + fm * 16 + quad * 4;
        int b = m >> 11, s0 = m & 2047;
        #pragma unroll
        for (int r = 0; r < 4; r++)
          dst[(((size_t)b * NH + h) * SEQ + s0 + r) * HS + d] = f2bf(acc[fm][fn][r] * s);
      }
    }
  } else { // v transposed: vt[b][h][d][s]
    #pragma unroll
    for (int fn = 0; fn < 4; fn++) {
      int c = nb + wn + fn * 16 + l15, h = c >> 6, d = c & 63;
      #pragma unroll
      for (int fm = 0; fm < 4; fm++) {
        int m = mt * 128 + wm + fm * 16 + quad * 4;
        int b = m >> 11, s0 = m & 2047;
        ushort4 pk;
        pk.x = f2bf(acc[fm][fn][0]); pk.y = f2bf(acc[fm][fn][1]);
        pk.z = f2bf(acc[fm][fn][2]); pk.w = f2bf(acc[fm][fn][3]);
        *(ushort4*)&vt[(((size_t)b * NH + h) * HS + d) * SEQ + s0] = pk;
      }
    }
  }
}

// ---- softmax + P^T pack for one fragment (S^T C-layout in regs) ----
template <bool MASKED>
__device__ __forceinline__ void soft_pack(const f32x4* s, float& ls,
                                          unsigned short* ptRow, int quad, int tmb) {
  #pragma unroll
  for (int tb = 0; tb < 4; tb++) {
    float pv[4];
    #pragma unroll
    for (int r = 0; r < 4; r++) {
      float p = exp2f(s[tb][r]);
      if (MASKED) { if (tmb + tb * 16 + quad * 4 + r > 0) p = 0.f; }
      ls += p;
      pv[r] = p;
    }
    ushort4 pk;
    pk.x = f2bf_fast(pv[0]); pk.y = f2bf_fast(pv[1]);
    pk.z = f2bf_fast(pv[2]); pk.w = f2bf_fast(pv[3]);
    *(ushort4*)&ptRow[tb * 16 + quad * 4] = pk;
  }
}

// ---- one kv-tile: S^T = K·Q^T, softmax, O^T += V·P^T.  MODE 0=free 1=mask f0 2=skip f0,mask f1
template <int MODE>
__device__ __forceinline__ void attn_tile(
    const unsigned short (&Kb)[64][72], const unsigned short (&Vb)[64][72],
    unsigned short* p0row, unsigned short* p1row,
    const bf16x8 (&qf)[2][2], float (&lsum)[2], f32x4 (&accO)[2][4],
    int quad, int l15, int tmb) {
  constexpr bool F0 = (MODE < 2);
  f32x4 s0[4], s1[4];
  #pragma unroll
  for (int tb = 0; tb < 4; tb++) { s0[tb] = (f32x4){0,0,0,0}; s1[tb] = (f32x4){0,0,0,0}; }
  #pragma unroll
  for (int tb = 0; tb < 4; tb++)
    #pragma unroll
    for (int hh = 0; hh < 2; hh++) {
      bf16x8 kf = *reinterpret_cast<const bf16x8*>(&Kb[tb * 16 + l15][hh * 32 + quad * 8]);
      if (F0) s0[tb] = __builtin_amdgcn_mfma_f32_16x16x32_bf16(kf, qf[0][hh], s0[tb], 0, 0, 0);
      s1[tb] = __builtin_amdgcn_mfma_f32_16x16x32_bf16(kf, qf[1][hh], s1[tb], 0, 0, 0);
    }
  if (MODE == 0) {
    soft_pack<false>(s0, lsum[0], p0row, quad, 0);
    soft_pack<false>(s1, lsum[1], p1row, quad, 0);
  } else if (MODE == 1) {
    soft_pack<true >(s0, lsum[0], p0row, quad, tmb);
    soft_pack<false>(s1, lsum[1], p1row, quad, 0);
  } else {
    soft_pack<true >(s1, lsum[1], p1row, quad, tmb);
  }
  bf16x8 bq0[2], bq1[2];
  #pragma unroll
  for (int tp = 0; tp < 2; tp++) {
    if (F0) bq0[tp] = *reinterpret_cast<const bf16x8*>(&p0row[tp * 32 + quad * 8]);
    bq1[tp] = *reinterpret_cast<const bf16x8*>(&p1row[tp * 32 + quad * 8]);
  }
  #pragma unroll
  for (int db = 0; db < 4; db++)
    #pragma unroll
    for (int tp = 0; tp < 2; tp++) {
      bf16x8 vf = *reinterpret_cast<const bf16x8*>(&Vb[db * 16 + l15][tp * 32 + quad * 8]);
      if (F0) accO[0][db] = __builtin_amdgcn_mfma_f32_16x16x32_bf16(vf, bq0[tp], accO[0][db], 0, 0, 0);
      accO[1][db] = __builtin_amdgcn_mfma_f32_16x16x32_bf16(vf, bq1[tp], accO[1][db], 0, 0, 0);
    }
}

// ---- flash attention: 128 q-rows/block, S^T scheme, LDS dbuf + reg prefetch.
//      bh_base splits the dispatch for profiling visibility. ----
__global__ __launch_bounds__(256) void attn_k(
    const unsigned short* __restrict__ q,
    const unsigned short* __restrict__ k,
    const unsigned short* __restrict__ vt,
    unsigned short* __restrict__ y, int bh_base) {
  __shared__ __attribute__((aligned(16))) unsigned short Kl[2][64][72];
  __shared__ __attribute__((aligned(16))) unsigned short Vl[2][64][72];
  __shared__ __attribute__((aligned(16))) unsigned short Pt[4][16][152];

  int st = (int)gridDim.x - 1 - (int)blockIdx.x;   // heavy-first
  int bh = bh_base + blockIdx.y, b = bh >> 4, h = bh & 15;
  const unsigned short* Q = q  + ((size_t)bh * SEQ + st * 128) * HS;
  const unsigned short* K = k  + (size_t)bh * SEQ * HS;
  const unsigned short* V = vt + (size_t)bh * HS * SEQ;   // [d][s]
  int tid = threadIdx.x, wave = tid >> 6, lane = tid & 63;
  int quad = lane >> 4, l15 = lane & 15;
  int lr = tid >> 3, lc = (tid & 7) * 8;

  bf16x8 qf[2][2];
  #pragma unroll
  for (int f = 0; f < 2; f++)
    #pragma unroll
    for (int hh = 0; hh < 2; hh++)
      qf[f][hh] = *reinterpret_cast<const bf16x8*>(
          &Q[(size_t)(f * 64 + wave * 16 + l15) * HS + hh * 32 + quad * 8]);

  float lsum[2] = {0.f, 0.f};
  f32x4 accO[2][4];
  #pragma unroll
  for (int f = 0; f < 2; f++)
    #pragma unroll
    for (int i = 0; i < 4; i++) accO[f][i] = (f32x4){0.f, 0.f, 0.f, 0.f};

  unsigned short* p0row = &Pt[wave][l15][0];
  unsigned short* p1row = &Pt[wave][l15][64];
  int tmb = -(wave * 16 + l15);

  uint4 kr0, kr1, vr0, vr1;
  auto g2r = [&](int kv) {
    kr0 = *(const uint4*)&K[(size_t)(kv * 64 + lr) * HS + lc];
    kr1 = *(const uint4*)&K[(size_t)(kv * 64 + lr + 32) * HS + lc];
    vr0 = *(const uint4*)&V[(size_t)lr * SEQ + kv * 64 + lc];
    vr1 = *(const uint4*)&V[(size_t)(lr + 32) * SEQ + kv * 64 + lc];
  };
  auto r2l = [&](int nb) {
    *(uint4*)&Kl[nb][lr][lc] = kr0; *(uint4*)&Kl[nb][lr + 32][lc] = kr1;
    *(uint4*)&Vl[nb][lr][lc] = vr0; *(uint4*)&Vl[nb][lr + 32][lc] = vr1;
  };

  int last = 2 * st + 1;
  g2r(0); r2l(0);
  __syncthreads();
  for (int kv = 0; kv <= last; kv++) {
    int cb = kv & 1;
    if (kv < last) g2r(kv + 1);
    if (kv < 2 * st)
      attn_tile<0>(Kl[cb], Vl[cb], p0row, p1row, qf, lsum, accO, quad, l15, tmb);
    else if (kv == 2 * st)
      attn_tile<1>(Kl[cb], Vl[cb], p0row, p1row, qf, lsum, accO, quad, l15, tmb);
    else
      attn_tile<2>(Kl[cb], Vl[cb], p0row, p1row, qf, lsum, accO, quad, l15, tmb);
    if (kv < last) r2l(cb ^ 1);
    __syncthreads();
  }

  #pragma unroll
  for (int f = 0; f < 2; f++) {
    float rs = lsum[f];
    rs += __shfl_xor(rs, 16); rs += __shfl_xor(rs, 32);
    float inv = 1.0f / fmaxf(rs, 1e-30f);
    int srow = st * 128 + f * 64 + wave * 16 + l15;
    #pragma unroll
    for (int db = 0; db < 4; db++) {
      ushort4 pk;
      pk.x = f2bf(accO[f][db][0] * inv); pk.y = f2bf(accO[f][db][1] * inv);
      pk.z = f2bf(accO[f][db][2] * inv); pk.w = f2bf(accO[f][db][3] * inv);
      *(ushort4*)&y[((size_t)b * SEQ + srow) * HDIM + h * 64 + db * 16 + quad * 4] = pk;
    }
  }
}

// ---- output projection, m97-style + swizzle -> fp32 out ----
__global__ __launch_bounds__(256) void out_gemm(
    const unsigned short* __restrict__ y,
    const unsigned short* __restrict__ wot,
    const void* __restrict__ bo,
    float* __restrict__ out) {
  __shared__ __attribute__((aligned(16))) unsigned short Al[128 * 64];
  __shared__ __attribute__((aligned(16))) unsigned short Bl[128 * 64];
  int tid = threadIdx.x;
  int fbo = detect_flag_block(bo, 512, tid, 256);
  int mt = blockIdx.x, nt = blockIdx.y;
  const unsigned short* A  = y   + (size_t)mt * 128 * HDIM;
  const unsigned short* Bm = wot + (size_t)nt * 128 * HDIM;
  int wave = tid >> 6, lane = tid & 63;
  int quad = lane >> 4, l15 = lane & 15;
  int r8 = lane >> 3, c8 = lane & 7;
  int gcol = ((c8 ^ r8) << 3);
  int x7 = l15 & 7;
  int wm = (wave >> 1) * 64, wn = (wave & 1) * 64;
  f32x4 acc[4][4];
  #pragma unroll
  for (int i = 0; i < 4; i++)
    #pragma unroll
    for (int j = 0; j < 4; j++) acc[i][j] = (f32x4){0.f, 0.f, 0.f, 0.f};

  for (int k0 = 0; k0 < HDIM; k0 += 64) {
    #pragma unroll
    for (int c = 0; c < 4; c++) {
      int row = wave * 32 + c * 8 + r8;
      gl_lds16(&A [(size_t)row * HDIM + k0 + gcol], &Al[(wave * 32 + c * 8) * 64]);
      gl_lds16(&Bm[(size_t)row * HDIM + k0 + gcol], &Bl[(wave * 32 + c * 8) * 64]);
    }
    __syncthreads();
    #pragma unroll
    for (int h = 0; h < 2; h++) {
      int cq = ((quad + 4 * h) ^ x7) << 3;
      bf16x8 af[4], bfr[4];
      #pragma unroll
      for (int fm = 0; fm < 4; fm++)
        af[fm] = *reinterpret_cast<const bf16x8*>(&Al[(wm + fm * 16 + l15) * 64 + cq]);
      #pragma unroll
      for (int fn = 0; fn < 4; fn++)
        bfr[fn] = *reinterpret_cast<const bf16x8*>(&Bl[(wn + fn * 16 + l15) * 64 + cq]);
      #pragma unroll
      for (int fm = 0; fm < 4; fm++)
        #pragma unroll
        for (int fn = 0; fn < 4; fn++)
          acc[fm][fn] = __builtin_amdgcn_mfma_f32_16x16x32_bf16(af[fm], bfr[fn], acc[fm][fn], 0, 0, 0);
    }
    __syncthreads();
  }

  #pragma unroll
  for (int fn = 0; fn < 4; fn++) {
    int n = nt * 128 + wn + fn * 16 + l15;
    float bias = load_elem(bo, fbo, n);
    #pragma unroll
    for (int fm = 0; fm < 4; fm++) {
      int m = mt * 128 + wm + fm * 16 + quad * 4;
      #pragma unroll
      for (int r = 0; r < 4; r++)
        out[(size_t)(m + r) * CH + n] = acc[fm][fn][r] + bias;
    }
  }
}

extern "C" void kernel_launch(void* const* d_in, const int* in_sizes, int n_in,
                              void* d_out, int out_size, void* d_ws, size_t ws_size,
                              hipStream_t stream) {
  const void* x  = d_in[0];
  const void* Wq = d_in[1];
  const void* Wk = d_in[2];
  const void* Wv = d_in[3];
  const void* Wo = d_in[4];
  const void* bo = d_in[5];
  float* out = (float*)d_out;

  char* ws = (char*)d_ws;
  const size_t MB = 1024 * 1024;
  unsigned short* qb   = (unsigned short*)(ws + 0);        // [B,H,S,D]  8MB (pre-scaled)
  unsigned short* kb   = (unsigned short*)(ws + 8  * MB);  // [B,H,S,D]  8MB
  unsigned short* vtb  = (unsigned short*)(ws + 16 * MB);  // [B,H,D,S]  8MB
  unsigned short* yb   = (unsigned short*)(ws + 24 * MB);  // [B,S,HD]   8MB
  unsigned short* wall = (unsigned short*)(ws + 32 * MB);  // [3][H,D,C] 6MB contiguous
  unsigned short* wot  = (unsigned short*)(ws + 38 * MB);  // [C,HD]     2MB
  unsigned short* xb   = (unsigned short*)(ws + 40 * MB);  // [B,S,C]    8MB bf16

  ingest_x<<<2048, 256, 0, stream>>>(x, xb);
  transpose3_k<<<dim3(HS / 32, CH / 32, 48), dim3(32, 8), 0, stream>>>(Wq, Wk, Wv, wall);
  transpose_k<<<dim3(CH / 32, HDIM / 32), dim3(32, 8), 0, stream>>>(Wo, wot, HDIM, CH);

  qkv_gemm<<<dim3(NB * SEQ / 128, 3 * HDIM / 128), 256, 0, stream>>>(xb, wall, qb, kb, vtb);
  attn_k<<<dim3(SEQ / 128, NH), 256, 0, stream>>>(qb, kb, vtb, yb, 0);
  attn_k<<<dim3(SEQ / 128, NH), 256, 0, stream>>>(qb, kb, vtb, yb, NH);
  out_gemm<<<dim3(NB * SEQ / 128, CH / 128), 256, 0, stream>>>(yb, wot, bo, out);
}

// Round 10
// 209.358 us; speedup vs baseline: 1.4300x; 1.3679x over previous
//
#include <hip/hip_runtime.h>
#include <cstdint>
#include <cstddef>

constexpr int SEQ  = 2048;
constexpr int CH   = 1024;
constexpr int NH   = 16;
constexpr int HS   = 64;
constexpr int NB   = 2;
constexpr int HDIM = NH * HS; // 1024

typedef __bf16 bf16x8 __attribute__((ext_vector_type(8)));
typedef float  f32x4  __attribute__((ext_vector_type(4)));

__device__ __forceinline__ unsigned short f2bf(float f) {
  union { float f; unsigned u; } v; v.f = f;
  unsigned u = v.u;
  u += 0x7fffu + ((u >> 16) & 1u);   // RNE
  return (unsigned short)(u >> 16);
}
__device__ __forceinline__ unsigned short f2bf_fast(float f) {
  union { float f; unsigned u; } v; v.f = f;
  return (unsigned short)((v.u + 0x8000u) >> 16);
}
__device__ __forceinline__ float bf2f(unsigned short h) {
  union { unsigned u; float f; } v; v.u = ((unsigned)h) << 16;
  return v.f;
}
__device__ __forceinline__ float load_elem(const void* p, int flag, size_t idx) {
  if (flag) return ((const float*)p)[idx];
  return bf2f(((const unsigned short*)p)[idx]);
}
__device__ __forceinline__ void gl_lds16(const unsigned short* g, unsigned short* l) {
  __builtin_amdgcn_global_load_lds(
      (const __attribute__((address_space(1))) unsigned int*)g,
      (__attribute__((address_space(3))) unsigned int*)l, 16, 0, 0);
}

// ---- inline dtype detector (observed: inputs fp32; kept as insurance) ----
__device__ int detect_flag_block(const void* p, int n, int tid, int nthr) {
  __shared__ int det_good;
  if (tid == 0) det_good = 0;
  __syncthreads();
  const unsigned short* u = (const unsigned short*)p;
  int good = 0;
  for (int j = tid; j < n; j += nthr) {
    unsigned short v = u[2 * j];
    int e = (v >> 7) & 0xFF;
    if (v != 0 && e >= 90 && e <= 150) good++;
  }
  atomicAdd(&det_good, good);
  __syncthreads();
  return (det_good * 10 >= n * 7) ? 0 : 1;   // 0 = bf16, 1 = fp32
}

// ---- fused preprocessing: ingest x + transpose Wq/Wk/Wv + transpose Wo ----
// blocks [0,1024): x -> bf16.  [1024,4096): Wq/Wk/Wv [H,C,D]->[H,D,C].
// [4096,5120): Wo [HD,C] -> [C,HD].
__global__ __launch_bounds__(256) void prep(
    const void* __restrict__ x,  const void* __restrict__ wq,
    const void* __restrict__ wk, const void* __restrict__ wv,
    const void* __restrict__ wo,
    unsigned short* __restrict__ xb,
    unsigned short* __restrict__ wall,   // [3][H][D][C]
    unsigned short* __restrict__ wot) {  // [C][HD]
  __shared__ unsigned short tile[32][33];
  int idx = blockIdx.x, tid = threadIdx.x;
  if (idx < 1024) {
    int f = detect_flag_block(x, 512, tid, 256);
    size_t n4 = (size_t)NB * SEQ * CH / 4;
    for (size_t i = (size_t)idx * 256 + tid; i < n4; i += (size_t)1024 * 256) {
      ushort4 o;
      if (f) {
        float4 v = ((const float4*)x)[i];
        o.x = f2bf(v.x); o.y = f2bf(v.y); o.z = f2bf(v.z); o.w = f2bf(v.w);
      } else {
        o = ((const ushort4*)x)[i];
      }
      ((ushort4*)xb)[i] = o;
    }
  } else if (idx < 4096) {
    int j = idx - 1024;
    int which = j >> 10, hh = (j >> 6) & 15, sub = j & 63;
    const void* src = (which == 0) ? wq : (which == 1) ? wk : wv;
    int f = detect_flag_block(src, 512, tid, 256);
    int c0 = (sub & 1) * 32;        // over HS (64)
    int r0 = (sub >> 1) * 32;       // over CH (1024)
    int tx = tid & 31, ty = tid >> 5;
    size_t boff = (size_t)hh * CH * HS;
    for (int i = ty; i < 32; i += 8)
      tile[i][tx] = f2bf(load_elem(src, f, boff + (size_t)(r0 + i) * HS + c0 + tx));
    __syncthreads();
    unsigned short* d = wall + ((size_t)which * NH + hh) * HS * CH;
    for (int i = ty; i < 32; i += 8)
      d[(size_t)(c0 + i) * CH + r0 + tx] = tile[tx][i];
  } else {
    int sub = idx - 4096;
    int f = detect_flag_block(wo, 512, tid, 256);
    int c0 = (sub & 31) * 32;       // over CH (cols)
    int r0 = (sub >> 5) * 32;       // over HDIM (rows)
    int tx = tid & 31, ty = tid >> 5;
    for (int i = ty; i < 32; i += 8)
      tile[i][tx] = f2bf(load_elem(wo, f, (size_t)(r0 + i) * CH + c0 + tx));
    __syncthreads();
    for (int i = ty; i < 32; i += 8)
      wot[(size_t)(c0 + i) * HDIM + r0 + tx] = tile[tx][i];
  }
}

// ---- fused QKV GEMM, m97-style staging + XOR swizzle ----
__global__ __launch_bounds__(256) void qkv_gemm(
    const unsigned short* __restrict__ xb,
    const unsigned short* __restrict__ wall,   // [3072][1024]
    unsigned short* __restrict__ qo,
    unsigned short* __restrict__ ko,
    unsigned short* __restrict__ vt) {
  __shared__ __attribute__((aligned(16))) unsigned short Al[128 * 64];
  __shared__ __attribute__((aligned(16))) unsigned short Bl[128 * 64];
  int mt = blockIdx.x, nt = blockIdx.y;
  const unsigned short* A  = xb   + (size_t)mt * 128 * CH;
  const unsigned short* Bm = wall + (size_t)nt * 128 * CH;
  int tid = threadIdx.x, wave = tid >> 6, lane = tid & 63;
  int quad = lane >> 4, l15 = lane & 15;
  int r8 = lane >> 3, c8 = lane & 7;
  int gcol = ((c8 ^ r8) << 3);
  int x7 = l15 & 7;
  int wm = (wave >> 1) * 64, wn = (wave & 1) * 64;
  f32x4 acc[4][4];
  #pragma unroll
  for (int i = 0; i < 4; i++)
    #pragma unroll
    for (int j = 0; j < 4; j++) acc[i][j] = (f32x4){0.f, 0.f, 0.f, 0.f};

  for (int k0 = 0; k0 < CH; k0 += 64) {
    #pragma unroll
    for (int c = 0; c < 4; c++) {
      int row = wave * 32 + c * 8 + r8;
      gl_lds16(&A [(size_t)row * CH + k0 + gcol], &Al[(wave * 32 + c * 8) * 64]);
      gl_lds16(&Bm[(size_t)row * CH + k0 + gcol], &Bl[(wave * 32 + c * 8) * 64]);
    }
    __syncthreads();
    #pragma unroll
    for (int h = 0; h < 2; h++) {
      int cq = ((quad + 4 * h) ^ x7) << 3;
      bf16x8 af[4], bfr[4];
      #pragma unroll
      for (int fm = 0; fm < 4; fm++)
        af[fm] = *reinterpret_cast<const bf16x8*>(&Al[(wm + fm * 16 + l15) * 64 + cq]);
      #pragma unroll
      for (int fn = 0; fn < 4; fn++)
        bfr[fn] = *reinterpret_cast<const bf16x8*>(&Bl[(wn + fn * 16 + l15) * 64 + cq]);
      #pragma unroll
      for (int fm = 0; fm < 4; fm++)
        #pragma unroll
        for (int fn = 0; fn < 4; fn++)
          acc[fm][fn] = __builtin_amdgcn_mfma_f32_16x16x32_bf16(af[fm], bfr[fn], acc[fm][fn], 0, 0, 0);
    }
    __syncthreads();
  }

  int seg = (nt * 128) >> 10;
  int nb  = (nt * 128) & 1023;
  if (seg < 2) {
    unsigned short* dst = (seg == 0) ? qo : ko;
    float s = (seg == 0) ? 0.18033688011112042f : 1.0f;  // 0.125*log2(e) folded into q
    #pragma unroll
    for (int fn = 0; fn < 4; fn++) {
      int c = nb + wn + fn * 16 + l15, h = c >> 6, d = c & 63;
      #pragma unroll
      for (int fm = 0; fm < 4; fm++) {
        int m = mt * 128 + wm + fm * 16 + quad * 4;
        int b = m >> 11, s0 = m & 2047;
        #pragma unroll
        for (int r = 0; r < 4; r++)
          dst[(((size_t)b * NH + h) * SEQ + s0 + r) * HS + d] = f2bf(acc[fm][fn][r] * s);
      }
    }
  } else { // v transposed: vt[b][h][d][s]
    #pragma unroll
    for (int fn = 0; fn < 4; fn++) {
      int c = nb + wn + fn * 16 + l15, h = c >> 6, d = c & 63;
      #pragma unroll
      for (int fm = 0; fm < 4; fm++) {
        int m = mt * 128 + wm + fm * 16 + quad * 4;
        int b = m >> 11, s0 = m & 2047;
        ushort4 pk;
        pk.x = f2bf(acc[fm][fn][0]); pk.y = f2bf(acc[fm][fn][1]);
        pk.z = f2bf(acc[fm][fn][2]); pk.w = f2bf(acc[fm][fn][3]);
        *(ushort4*)&vt[(((size_t)b * NH + h) * HS + d) * SEQ + s0] = pk;
      }
    }
  }
}

// ---- softmax + P^T pack for one fragment (S^T C-layout in regs) ----
template <bool MASKED>
__device__ __forceinline__ void soft_pack(const f32x4* s, float& ls,
                                          unsigned short* ptRow, int quad, int tmb) {
  #pragma unroll
  for (int tb = 0; tb < 4; tb++) {
    float pv[4];
    #pragma unroll
    for (int r = 0; r < 4; r++) {
      float p = exp2f(s[tb][r]);
      if (MASKED) { if (tmb + tb * 16 + quad * 4 + r > 0) p = 0.f; }
      ls += p;
      pv[r] = p;
    }
    ushort4 pk;
    pk.x = f2bf_fast(pv[0]); pk.y = f2bf_fast(pv[1]);
    pk.z = f2bf_fast(pv[2]); pk.w = f2bf_fast(pv[3]);
    *(ushort4*)&ptRow[tb * 16 + quad * 4] = pk;
  }
}

// ---- one kv-tile for the paired-block scheme.
// MODE: 0 = both sides free; 1 = side0 masked + side1 free;
//       2 = side1 only, free; 3 = side1 only, masked.
template <int MODE>
__device__ __forceinline__ void attn_tile(
    const unsigned short (&Kb)[64][72], const unsigned short (&Vb)[64][72],
    unsigned short* p0row, unsigned short* p1row,
    const bf16x8 (&qf)[2][2], float (&lsum)[2], f32x4 (&accO)[2][4],
    int quad, int l15, int tmb) {
  constexpr bool C0 = (MODE <= 1);
  constexpr bool M0 = (MODE == 1);
  constexpr bool M1 = (MODE == 3);
  f32x4 s0[4], s1[4];
  #pragma unroll
  for (int tb = 0; tb < 4; tb++) { s0[tb] = (f32x4){0,0,0,0}; s1[tb] = (f32x4){0,0,0,0}; }
  #pragma unroll
  for (int tb = 0; tb < 4; tb++)
    #pragma unroll
    for (int hh = 0; hh < 2; hh++) {
      bf16x8 kf = *reinterpret_cast<const bf16x8*>(&Kb[tb * 16 + l15][hh * 32 + quad * 8]);
      if (C0) s0[tb] = __builtin_amdgcn_mfma_f32_16x16x32_bf16(kf, qf[0][hh], s0[tb], 0, 0, 0);
      s1[tb] = __builtin_amdgcn_mfma_f32_16x16x32_bf16(kf, qf[1][hh], s1[tb], 0, 0, 0);
    }
  if (C0) soft_pack<M0>(s0, lsum[0], p0row, quad, tmb);
  soft_pack<M1>(s1, lsum[1], p1row, quad, tmb);

  bf16x8 bq0[2], bq1[2];
  #pragma unroll
  for (int tp = 0; tp < 2; tp++) {
    if (C0) bq0[tp] = *reinterpret_cast<const bf16x8*>(&p0row[tp * 32 + quad * 8]);
    bq1[tp] = *reinterpret_cast<const bf16x8*>(&p1row[tp * 32 + quad * 8]);
  }
  #pragma unroll
  for (int db = 0; db < 4; db++)
    #pragma unroll
    for (int tp = 0; tp < 2; tp++) {
      bf16x8 vf = *reinterpret_cast<const bf16x8*>(&Vb[db * 16 + l15][tp * 32 + quad * 8]);
      if (C0) accO[0][db] = __builtin_amdgcn_mfma_f32_16x16x32_bf16(vf, bq0[tp], accO[0][db], 0, 0, 0);
      accO[1][db] = __builtin_amdgcn_mfma_f32_16x16x32_bf16(vf, bq1[tp], accO[1][db], 0, 0, 0);
    }
}

// ---- flash attention, paired-supertile balanced blocks:
// block (p, bh) handles q-supertiles st0=p and st1=31-p (constant 33 sub-tiles).
// K/V staging shared between the sides; LDS dbuf + reg prefetch; 1 barrier/tile.
__global__ __launch_bounds__(256) void attn_k(
    const unsigned short* __restrict__ q,
    const unsigned short* __restrict__ k,
    const unsigned short* __restrict__ vt,
    unsigned short* __restrict__ y) {
  __shared__ __attribute__((aligned(16))) unsigned short Kl[2][64][72];
  __shared__ __attribute__((aligned(16))) unsigned short Vl[2][64][72];
  __shared__ __attribute__((aligned(16))) unsigned short Pt[4][16][152];

  int p = blockIdx.x;                 // 0..15
  int st0 = p, st1 = 31 - p;          // st0 < 16 <= st1
  int bh = blockIdx.y, b = bh >> 4, h = bh & 15;
  const unsigned short* Q0 = q + ((size_t)bh * SEQ + st0 * 64) * HS;
  const unsigned short* Q1 = q + ((size_t)bh * SEQ + st1 * 64) * HS;
  const unsigned short* K  = k  + (size_t)bh * SEQ * HS;
  const unsigned short* V  = vt + (size_t)bh * HS * SEQ;   // [d][s]
  int tid = threadIdx.x, wave = tid >> 6, lane = tid & 63;
  int quad = lane >> 4, l15 = lane & 15;
  int lr = tid >> 3, lc = (tid & 7) * 8;

  bf16x8 qf[2][2];
  #pragma unroll
  for (int hh = 0; hh < 2; hh++) {
    qf[0][hh] = *reinterpret_cast<const bf16x8*>(
        &Q0[(size_t)(wave * 16 + l15) * HS + hh * 32 + quad * 8]);
    qf[1][hh] = *reinterpret_cast<const bf16x8*>(
        &Q1[(size_t)(wave * 16 + l15) * HS + hh * 32 + quad * 8]);
  }

  float lsum[2] = {0.f, 0.f};
  f32x4 accO[2][4];
  #pragma unroll
  for (int f = 0; f < 2; f++)
    #pragma unroll
    for (int i = 0; i < 4; i++) accO[f][i] = (f32x4){0.f, 0.f, 0.f, 0.f};

  unsigned short* p0row = &Pt[wave][l15][0];
  unsigned short* p1row = &Pt[wave][l15][64];
  int tmb = -(wave * 16 + l15);

  uint4 kr0, kr1, vr0, vr1;
  auto g2r = [&](int kv) {
    kr0 = *(const uint4*)&K[(size_t)(kv * 64 + lr) * HS + lc];
    kr1 = *(const uint4*)&K[(size_t)(kv * 64 + lr + 32) * HS + lc];
    vr0 = *(const uint4*)&V[(size_t)lr * SEQ + kv * 64 + lc];
    vr1 = *(const uint4*)&V[(size_t)(lr + 32) * SEQ + kv * 64 + lc];
  };
  auto r2l = [&](int nb) {
    *(uint4*)&Kl[nb][lr][lc] = kr0; *(uint4*)&Kl[nb][lr + 32][lc] = kr1;
    *(uint4*)&Vl[nb][lr][lc] = vr0; *(uint4*)&Vl[nb][lr + 32][lc] = vr1;
  };

  int last = st1;
  g2r(0); r2l(0);
  __syncthreads();
  for (int kv = 0; kv <= last; kv++) {
    int cb = kv & 1;
    if (kv < last) g2r(kv + 1);
    if (kv < st0)
      attn_tile<0>(Kl[cb], Vl[cb], p0row, p1row, qf, lsum, accO, quad, l15, tmb);
    else if (kv == st0)
      attn_tile<1>(Kl[cb], Vl[cb], p0row, p1row, qf, lsum, accO, quad, l15, tmb);
    else if (kv < st1)
      attn_tile<2>(Kl[cb], Vl[cb], p0row, p1row, qf, lsum, accO, quad, l15, tmb);
    else
      attn_tile<3>(Kl[cb], Vl[cb], p0row, p1row, qf, lsum, accO, quad, l15, tmb);
    if (kv < last) r2l(cb ^ 1);
    __syncthreads();
  }

  // epilogue: reduce per-lane l over quads, normalize, write both sides
  #pragma unroll
  for (int f = 0; f < 2; f++) {
    float rs = lsum[f];
    rs += __shfl_xor(rs, 16); rs += __shfl_xor(rs, 32);
    float inv = 1.0f / fmaxf(rs, 1e-30f);
    int srow = (f == 0 ? st0 : st1) * 64 + wave * 16 + l15;
    #pragma unroll
    for (int db = 0; db < 4; db++) {
      ushort4 pk;
      pk.x = f2bf(accO[f][db][0] * inv); pk.y = f2bf(accO[f][db][1] * inv);
      pk.z = f2bf(accO[f][db][2] * inv); pk.w = f2bf(accO[f][db][3] * inv);
      *(ushort4*)&y[((size_t)b * SEQ + srow) * HDIM + h * 64 + db * 16 + quad * 4] = pk;
    }
  }
}

// ---- output projection, m97-style + swizzle -> fp32 out ----
__global__ __launch_bounds__(256) void out_gemm(
    const unsigned short* __restrict__ y,
    const unsigned short* __restrict__ wot,
    const void* __restrict__ bo,
    float* __restrict__ out) {
  __shared__ __attribute__((aligned(16))) unsigned short Al[128 * 64];
  __shared__ __attribute__((aligned(16))) unsigned short Bl[128 * 64];
  int tid = threadIdx.x;
  int fbo = detect_flag_block(bo, 512, tid, 256);
  int mt = blockIdx.x, nt = blockIdx.y;
  const unsigned short* A  = y   + (size_t)mt * 128 * HDIM;
  const unsigned short* Bm = wot + (size_t)nt * 128 * HDIM;
  int wave = tid >> 6, lane = tid & 63;
  int quad = lane >> 4, l15 = lane & 15;
  int r8 = lane >> 3, c8 = lane & 7;
  int gcol = ((c8 ^ r8) << 3);
  int x7 = l15 & 7;
  int wm = (wave >> 1) * 64, wn = (wave & 1) * 64;
  f32x4 acc[4][4];
  #pragma unroll
  for (int i = 0; i < 4; i++)
    #pragma unroll
    for (int j = 0; j < 4; j++) acc[i][j] = (f32x4){0.f, 0.f, 0.f, 0.f};

  for (int k0 = 0; k0 < HDIM; k0 += 64) {
    #pragma unroll
    for (int c = 0; c < 4; c++) {
      int row = wave * 32 + c * 8 + r8;
      gl_lds16(&A [(size_t)row * HDIM + k0 + gcol], &Al[(wave * 32 + c * 8) * 64]);
      gl_lds16(&Bm[(size_t)row * HDIM + k0 + gcol], &Bl[(wave * 32 + c * 8) * 64]);
    }
    __syncthreads();
    #pragma unroll
    for (int h = 0; h < 2; h++) {
      int cq = ((quad + 4 * h) ^ x7) << 3;
      bf16x8 af[4], bfr[4];
      #pragma unroll
      for (int fm = 0; fm < 4; fm++)
        af[fm] = *reinterpret_cast<const bf16x8*>(&Al[(wm + fm * 16 + l15) * 64 + cq]);
      #pragma unroll
      for (int fn = 0; fn < 4; fn++)
        bfr[fn] = *reinterpret_cast<const bf16x8*>(&Bl[(wn + fn * 16 + l15) * 64 + cq]);
      #pragma unroll
      for (int fm = 0; fm < 4; fm++)
        #pragma unroll
        for (int fn = 0; fn < 4; fn++)
          acc[fm][fn] = __builtin_amdgcn_mfma_f32_16x16x32_bf16(af[fm], bfr[fn], acc[fm][fn], 0, 0, 0);
    }
    __syncthreads();
  }

  #pragma unroll
  for (int fn = 0; fn < 4; fn++) {
    int n = nt * 128 + wn + fn * 16 + l15;
    float bias = load_elem(bo, fbo, n);
    #pragma unroll
    for (int fm = 0; fm < 4; fm++) {
      int m = mt * 128 + wm + fm * 16 + quad * 4;
      #pragma unroll
      for (int r = 0; r < 4; r++)
        out[(size_t)(m + r) * CH + n] = acc[fm][fn][r] + bias;
    }
  }
}

extern "C" void kernel_launch(void* const* d_in, const int* in_sizes, int n_in,
                              void* d_out, int out_size, void* d_ws, size_t ws_size,
                              hipStream_t stream) {
  const void* x  = d_in[0];
  const void* Wq = d_in[1];
  const void* Wk = d_in[2];
  const void* Wv = d_in[3];
  const void* Wo = d_in[4];
  const void* bo = d_in[5];
  float* out = (float*)d_out;

  char* ws = (char*)d_ws;
  const size_t MB = 1024 * 1024;
  unsigned short* qb   = (unsigned short*)(ws + 0);        // [B,H,S,D]  8MB (pre-scaled)
  unsigned short* kb   = (unsigned short*)(ws + 8  * MB);  // [B,H,S,D]  8MB
  unsigned short* vtb  = (unsigned short*)(ws + 16 * MB);  // [B,H,D,S]  8MB
  unsigned short* yb   = (unsigned short*)(ws + 24 * MB);  // [B,S,HD]   8MB
  unsigned short* wall = (unsigned short*)(ws + 32 * MB);  // [3][H,D,C] 6MB contiguous
  unsigned short* wot  = (unsigned short*)(ws + 38 * MB);  // [C,HD]     2MB
  unsigned short* xb   = (unsigned short*)(ws + 40 * MB);  // [B,S,C]    8MB bf16

  prep<<<5120, 256, 0, stream>>>(x, Wq, Wk, Wv, Wo, xb, wall, wot);
  qkv_gemm<<<dim3(NB * SEQ / 128, 3 * HDIM / 128), 256, 0, stream>>>(xb, wall, qb, kb, vtb);
  attn_k<<<dim3(16, NB * NH), 256, 0, stream>>>(qb, kb, vtb, yb);
  out_gemm<<<dim3(NB * SEQ / 128, CH / 128), 256, 0, stream>>>(yb, wot, bo, out);
}